// Round 8
// baseline (170.720 us; speedup 1.0000x reference)
//
#include <hip/hip_runtime.h>

// ---------------- helpers ----------------

typedef __bf16 bf16x8 __attribute__((ext_vector_type(8)));
typedef float  f32x4  __attribute__((ext_vector_type(4)));

__device__ __forceinline__ unsigned short f2bf(float x) {
    unsigned int u = __builtin_bit_cast(unsigned int, x);
    u = (u + 0x7fffu + ((u >> 16) & 1u)) >> 16;
    return (unsigned short)u;
}

__device__ __forceinline__ void gl2lds16(const unsigned short* g, unsigned short* l) {
    __builtin_amdgcn_global_load_lds(
        (const __attribute__((address_space(1))) unsigned int*)g,
        (__attribute__((address_space(3))) unsigned int*)l,
        16, 0, 0);
}

__device__ __forceinline__ float sigf(float x) {
    return __builtin_amdgcn_rcpf(1.f + __expf(-x));
}
__device__ __forceinline__ float tanh_fast(float x) {
    return 2.f * __builtin_amdgcn_rcpf(1.f + __expf(-2.f * x)) - 1.f;
}

// ---------------- fused conversion kernel ----------------
// blocks [0,16384): activations -> bf16 A [4096][4096]
// blocks [16384,32768): weights -> bf16 B^T with gate-interleave permutation
//   Bt[p][k] = Wcat[k][ g*1024 + u ],  p = (u>>5)*128 + ((u>>4)&1)*64 + g*16 + (u&15)
//   (derived for BN=128 blocks: lane lr of wave wn in block bc holds gates a,i,f,o
//    of unit u = bc*32 + wn*16 + lr in its 4 N-fragments)

__global__ void convert_AB(const float* __restrict__ A0, const float* __restrict__ A1,
                           const float* __restrict__ A2, const float* __restrict__ A3,
                           const float* __restrict__ Wb, const float* __restrict__ W1,
                           const float* __restrict__ W2, const float* __restrict__ Wl,
                           unsigned short* __restrict__ Abf,
                           unsigned short* __restrict__ Bt) {
    __shared__ float t[32][33];
    if (blockIdx.x < 16384) {
        int idx = blockIdx.x * 256 + threadIdx.x;
        int e0  = idx * 4;
        int b   = e0 >> 12;
        int k   = e0 & 4095;
        const float* S = (k < 1024) ? A0 : (k < 2048) ? A1 : (k < 3072) ? A2 : A3;
        int col = k & 1023;
        const float4 v = *reinterpret_cast<const float4*>(S + (size_t)b * 1024 + col);
        ushort4 o;
        o.x = f2bf(v.x); o.y = f2bf(v.y); o.z = f2bf(v.z); o.w = f2bf(v.w);
        *reinterpret_cast<ushort4*>(Abf + (size_t)b * 4096 + k) = o;
    } else {
        int tile = blockIdx.x - 16384;    // 128 j-tiles x 128 k-tiles
        int jt = tile & 127, kt = tile >> 7;
        int j0 = jt * 32, k0 = kt * 32;
        int ksel = k0 >> 10;
        const float* S = (ksel == 0) ? Wb : (ksel == 1) ? W1 : (ksel == 2) ? W2 : Wl;
        int kloc = k0 & 1023;
        int tx = threadIdx.x & 31, ty = threadIdx.x >> 5;
#pragma unroll
        for (int i = 0; i < 4; ++i) {
            int r = ty + i * 8;
            t[r][tx] = S[(size_t)(kloc + r) * 4096 + j0 + tx];
        }
        __syncthreads();
        int g = j0 >> 10;
        int nbase = j0 & 1023;
#pragma unroll
        for (int i = 0; i < 4; ++i) {
            int jj = ty + i * 8;
            int u  = nbase + jj;
            int p  = (u >> 5) * 128 + ((u >> 4) & 1) * 64 + g * 16 + (u & 15);
            Bt[(size_t)p * 4096 + k0 + tx] = f2bf(t[tx][jj]);
        }
    }
}

// ---------------- 256x128 GEMM, BK=32, 2 blocks/CU + fused LSTM epilogue ----------------
// A [4096][4096] bf16 row-major, Bt [4096(p)][4096(k)] bf16 row-major (B^T).
// 256 threads = 4 waves (2M x 2N); per wave 128x64 output = acc[8][4] f32x4 (same
// per-wave structure as the verified round-6 kernel). LDS 48 KB/block -> TWO
// independent blocks per CU: their waves are not barrier-synchronized, so one
// block's MFMA covers the other block's LDS/lgkm stalls (m114 mechanism; the
// 1-block 256^2 config was stuck at the serial ds_read+MFMA sum for 3 rounds).
// Swizzle for 64-B rows: byte ^= (row&3)<<4 (bank-floor, verified bijective).
// Dataflow: 2 barriers/K-tile, counted vmcnt(2) (A(t+1) drained, B(t+2) in flight).

__global__ __launch_bounds__(256, 2) void gemm_lstm(
        const unsigned short* __restrict__ A,
        const unsigned short* __restrict__ Bt,
        const float* __restrict__ bias,
        const float* __restrict__ cprev,
        float* __restrict__ out) {
    __shared__ unsigned short lds[24576];          // 48 KiB
#define ASB(b) (lds + (b) * 8192)                  // A buf: 256x32 bf16 = 16 KB
#define BSB(b) (lds + 16384 + (b) * 4096)          // B buf: 128x32 bf16 = 8 KB

    const int tid  = threadIdx.x;
    const int wid  = tid >> 6;
    const int lane = tid & 63;
    const int wm = wid >> 1, wn = wid & 1;         // 2 x 2 wave grid
    const int lr = lane & 15, lq = lane >> 4;
    const int bm = blockIdx.y, bc = blockIdx.x;

    // staging geometry: rows are 64 B (BK=32). One gl2lds pass = 256 thr x 16 B
    // = 4 KB = 64 rows; chunk (2 passes) = 128 rows.
    const int X0 = wid * 1024 + lane * 16;                 // bytes, [0,4096)
    const int rs = X0 >> 6;                                // row 0..63
    const int cs = ((X0 & 63) ^ ((rs & 3) << 4)) >> 1;     // element col (pre-swizzled src)
    const unsigned short* Agb = A  + ((size_t)(bm * 256 + rs)) * 4096 + cs;
    const unsigned short* Bgb = Bt + ((size_t)(bc * 128 + rs)) * 4096 + cs;

    // ds_read fragment col offset (elements), read-side swizzle ((row&3)<<4 on bytes)
    const int ca = ((lq * 16) ^ ((lr & 3) << 4)) >> 1;

    f32x4 acc[8][4] = {};                          // acc[mi][gate]

#define STAGE_A(b, h, kt) do {                                               \
        unsigned short* _d = ASB(b) + (h) * 4096 + wid * 512;                \
        const unsigned short* _s = Agb + (size_t)((h) * 128) * 4096 + (kt) * 32; \
        gl2lds16(_s, _d);                                                    \
        gl2lds16(_s + 64 * 4096, _d + 2048);                                 \
    } while (0)
#define STAGE_B(b, kt) do {                                                  \
        unsigned short* _d = BSB(b) + wid * 512;                             \
        const unsigned short* _s = Bgb + (size_t)(kt) * 32;                  \
        gl2lds16(_s, _d);                                                    \
        gl2lds16(_s + 64 * 4096, _d + 2048);                                 \
    } while (0)
#define LDA(buf, mi) (*reinterpret_cast<const bf16x8*>((buf) + (wm * 128 + (mi) * 16 + lr) * 32 + ca))
#define LDB(buf, ni) (*reinterpret_cast<const bf16x8*>((buf) + (wn * 64  + (ni) * 16 + lr) * 32 + ca))
#define RD_A(DST, BUF, MI0) do {                                             \
        _Pragma("unroll")                                                    \
        for (int m = 0; m < 2; ++m) DST[m] = LDA(BUF, (MI0) + m);            \
    } while (0)
#define RD_B(DST, BUF) do {                                                  \
        _Pragma("unroll")                                                    \
        for (int n = 0; n < 4; ++n) DST[n] = LDB(BUF, n);                    \
    } while (0)
#define SBAR() __builtin_amdgcn_s_barrier()
#define SFENCE() __builtin_amdgcn_sched_barrier(0)
#define VMFENCE() asm volatile("s_waitcnt vmcnt(2)" ::: "memory")
#define MFMA8(P, AF, BF)                                                     \
        __builtin_amdgcn_s_setprio(1);                                       \
        _Pragma("unroll")                                                    \
        for (int m = 0; m < 2; ++m)                                          \
        _Pragma("unroll")                                                    \
        for (int ni = 0; ni < 4; ++ni)                                       \
            acc[(P)*2 + m][ni] = __builtin_amdgcn_mfma_f32_16x16x32_bf16(    \
                AF[m], BF[ni], acc[(P)*2 + m][ni], 0, 0, 0);                 \
        __builtin_amdgcn_s_setprio(0)

#define KITER(T, PAR) do {                                                   \
        const unsigned short* Ac = ASB(PAR);                                 \
        const unsigned short* Bc = BSB(PAR);                                 \
        const int ktA = ((T) < 127) ? (T) + 1 : 127;                         \
        const int ktB = ((T) < 126) ? (T) + 2 : 127;                         \
        STAGE_A(PAR ^ 1, 0, ktA);                                            \
        STAGE_A(PAR ^ 1, 1, ktA);                                            \
        bf16x8 bfr[4];                                                       \
        bf16x8 af[2];                                                        \
        RD_B(bfr, Bc);                                                       \
        RD_A(af, Ac, 0);                                                     \
        SFENCE();                                                            \
        MFMA8(0, af, bfr);                                                   \
        SFENCE();                                                            \
        SBAR();   /* B2: all waves' B-frags in regs -> B region writable */  \
        STAGE_B(PAR, ktB);                                                   \
        RD_A(af, Ac, 2);                                                     \
        SFENCE();                                                            \
        MFMA8(1, af, bfr);                                                   \
        SFENCE();                                                            \
        RD_A(af, Ac, 4);                                                     \
        SFENCE();                                                            \
        MFMA8(2, af, bfr);                                                   \
        SFENCE();                                                            \
        RD_A(af, Ac, 6);                                                     \
        SFENCE();                                                            \
        MFMA8(3, af, bfr);                                                   \
        VMFENCE();                                                           \
        SBAR();   /* B1: tile T+1 staged data ready */                       \
    } while (0)

    // ---- prologue: tile0 A+B, tile1 B staged ----
    STAGE_A(0, 0, 0); STAGE_A(0, 1, 0);
    STAGE_B(0, 0);
    STAGE_B(1, 1);
    VMFENCE();                                     // tile0's 6 loads landed
    SBAR();

    for (int u = 0; u < 64; ++u) {
        KITER(2 * u, 0);
        KITER(2 * u + 1, 1);
    }

    // ---- fused LSTM epilogue: lane lr holds a,i,f,o of unit u in ni=0..3 ----
    const int un = bc * 32 + wn * 16 + lr;
    const float ba  = bias[un];
    const float bi  = bias[1024 + un];
    const float bfv = bias[2048 + un];
    const float bo  = bias[3072 + un];
    float* outh = out;
    float* outc = out + (size_t)4096 * 1024;

#pragma unroll
    for (int mi = 0; mi < 8; ++mi) {
        const int r0 = bm * 256 + wm * 128 + mi * 16 + lq * 4;
#pragma unroll
        for (int r = 0; r < 4; ++r) {
            const size_t off = (size_t)(r0 + r) * 1024 + un;
            const float a  = acc[mi][0][r] + ba;
            const float ii = acc[mi][1][r] + bi;
            const float ff = acc[mi][2][r] + bfv;
            const float oo = acc[mi][3][r] + bo;
            const float c  = tanh_fast(a) * sigf(ii) + sigf(ff) * cprev[off];
            outh[off] = sigf(oo) * tanh_fast(c);
            outc[off] = c;
        }
    }
#undef STAGE_A
#undef STAGE_B
#undef LDA
#undef LDB
#undef RD_A
#undef RD_B
#undef SBAR
#undef SFENCE
#undef VMFENCE
#undef MFMA8
#undef KITER
#undef ASB
#undef BSB
}

// ---------------- launch ----------------

extern "C" void kernel_launch(void* const* d_in, const int* in_sizes, int n_in,
                              void* d_out, int out_size, void* d_ws, size_t ws_size,
                              hipStream_t stream) {
    const float* top_buf = (const float*)d_in[0];
    const float* s1      = (const float*)d_in[1];
    const float* s2      = (const float*)d_in[2];
    const float* hprev   = (const float*)d_in[3];
    const float* cprev   = (const float*)d_in[4];
    const float* Wb      = (const float*)d_in[5];
    const float* W1      = (const float*)d_in[6];
    const float* W2      = (const float*)d_in[7];
    const float* Wl      = (const float*)d_in[8];
    const float* bl      = (const float*)d_in[9];

    unsigned short* Abf = (unsigned short*)d_ws;                 // 32 MB
    unsigned short* Bt  = Abf + (size_t)4096 * 4096;             // 32 MB

    convert_AB<<<32768, 256, 0, stream>>>(top_buf, s1, s2, hprev,
                                          Wb, W1, W2, Wl, Abf, Bt);

    dim3 grid(32, 16);
    gemm_lstm<<<grid, 256, 0, stream>>>(Abf, Bt, bl, cprev, (float*)d_out);
}

// Round 9
// 164.083 us; speedup vs baseline: 1.0404x; 1.0404x over previous
//
#include <hip/hip_runtime.h>

// ---------------- helpers ----------------

typedef __bf16 bf16x8 __attribute__((ext_vector_type(8)));
typedef float  f32x16 __attribute__((ext_vector_type(16)));

__device__ __forceinline__ unsigned short f2bf(float x) {
    unsigned int u = __builtin_bit_cast(unsigned int, x);
    u = (u + 0x7fffu + ((u >> 16) & 1u)) >> 16;
    return (unsigned short)u;
}

__device__ __forceinline__ void gl2lds16(const unsigned short* g, unsigned short* l) {
    __builtin_amdgcn_global_load_lds(
        (const __attribute__((address_space(1))) unsigned int*)g,
        (__attribute__((address_space(3))) unsigned int*)l,
        16, 0, 0);
}

__device__ __forceinline__ float sigf(float x) {
    return __builtin_amdgcn_rcpf(1.f + __expf(-x));
}
__device__ __forceinline__ float tanh_fast(float x) {
    return 2.f * __builtin_amdgcn_rcpf(1.f + __expf(-2.f * x)) - 1.f;
}

// ---------------- fused conversion kernel ----------------
// blocks [0,16384): activations -> bf16 A [4096][4096]
// blocks [16384,32768): weights -> bf16 B^T with gate-interleave permutation
//   Bt[p][k] = Wcat[k][ g*1024 + u ],  p = (u>>5)*128 + g*32 + (u&31)
//   (derived for 32x32 frags, N_frags=4: lane l31 of wave wn in block bc holds
//    gates a,i,f,o of unit u = bc*64 + wn*32 + l31 in its 4 ni-fragments)

__global__ void convert_AB(const float* __restrict__ A0, const float* __restrict__ A1,
                           const float* __restrict__ A2, const float* __restrict__ A3,
                           const float* __restrict__ Wb, const float* __restrict__ W1,
                           const float* __restrict__ W2, const float* __restrict__ Wl,
                           unsigned short* __restrict__ Abf,
                           unsigned short* __restrict__ Bt) {
    __shared__ float t[32][33];
    if (blockIdx.x < 16384) {
        int idx = blockIdx.x * 256 + threadIdx.x;
        int e0  = idx * 4;
        int b   = e0 >> 12;
        int k   = e0 & 4095;
        const float* S = (k < 1024) ? A0 : (k < 2048) ? A1 : (k < 3072) ? A2 : A3;
        int col = k & 1023;
        const float4 v = *reinterpret_cast<const float4*>(S + (size_t)b * 1024 + col);
        ushort4 o;
        o.x = f2bf(v.x); o.y = f2bf(v.y); o.z = f2bf(v.z); o.w = f2bf(v.w);
        *reinterpret_cast<ushort4*>(Abf + (size_t)b * 4096 + k) = o;
    } else {
        int tile = blockIdx.x - 16384;    // 128 j-tiles x 128 k-tiles
        int jt = tile & 127, kt = tile >> 7;
        int j0 = jt * 32, k0 = kt * 32;
        int ksel = k0 >> 10;
        const float* S = (ksel == 0) ? Wb : (ksel == 1) ? W1 : (ksel == 2) ? W2 : Wl;
        int kloc = k0 & 1023;
        int tx = threadIdx.x & 31, ty = threadIdx.x >> 5;
#pragma unroll
        for (int i = 0; i < 4; ++i) {
            int r = ty + i * 8;
            t[r][tx] = S[(size_t)(kloc + r) * 4096 + j0 + tx];
        }
        __syncthreads();
        int g = j0 >> 10;
        int nbase = j0 & 1023;
#pragma unroll
        for (int i = 0; i < 4; ++i) {
            int jj = ty + i * 8;
            int u  = nbase + jj;
            int p  = (u >> 5) * 128 + g * 32 + (u & 31);
            Bt[(size_t)p * 4096 + k0 + tx] = f2bf(t[tx][jj]);
        }
    }
}

// ---------------- 256x256 GEMM (32x32x16 MFMA) + fused LSTM epilogue ----------------
// A [4096][4096] bf16 row-major, Bt [4096(p)][4096(k)] bf16 row-major (B^T).
// 512 threads = 8 waves (4M x 2N); wave-tile 64x128 = acc[2 mi][4 ni] f32x16 (128 AGPR).
// BK=64; LDS 2 x (A 256x64 + B 256x64) = 128 KiB, XOR swizzle (row&7)<<4 (bank-floor).
// v_mfma_f32_32x32x16_bf16: measured ceiling 2495 TF (99.8% dense) vs ~2075 for
// 16x16x32 -> MFMA floor 66 -> 55 us at identical LDS traffic (24 b128/wave/K-tile).
// Dataflow: r6-verified 2 barriers/K-tile + counted vmcnt(4); explicit lgkmcnt(0)
// pin before B2 (all B-frag reads complete before B region becomes writable).

__global__ __launch_bounds__(512, 2) void gemm_lstm(
        const unsigned short* __restrict__ A,
        const unsigned short* __restrict__ Bt,
        const float* __restrict__ bias,
        const float* __restrict__ cprev,
        float* __restrict__ out) {
    __shared__ unsigned short lds[65536];          // 128 KiB
#define ASB(b) (lds + (b) * 16384)
#define BSB(b) (lds + 32768 + (b) * 16384)

    const int tid  = threadIdx.x;
    const int wid  = tid >> 6;
    const int lane = tid & 63;
    const int wm = wid >> 1, wn = wid & 1;         // 4M x 2N wave grid
    const int l31 = lane & 31, q5 = lane >> 5;
    const int bm = blockIdx.y, bc = blockIdx.x;

    // staging geometry: half-tile = 128 rows x 64 cols = 16 KB; 2 chunks/thread
    const int X0 = wid * 1024 + lane * 16;                 // bytes within half-region
    const int rs = X0 >> 7;
    const int cs = ((X0 & 127) ^ ((rs & 7) << 4)) >> 1;    // element col (pre-swizzled src)
    const unsigned short* Agb = A  + ((size_t)(bm * 256 + rs)) * 4096 + cs;
    const unsigned short* Bgb = Bt + ((size_t)(bc * 256 + rs)) * 4096 + cs;

    // ds_read col offsets (elements) for 32x32x16 frags: lane covers k = ks*16 + q5*8..+8
    // byte-in-row = q5*16 + ks*32, swizzled by ((row&7)<<4); row&7 == lane&7.
    int ca32[4];
#pragma unroll
    for (int ks = 0; ks < 4; ++ks)
        ca32[ks] = ((q5 * 16 + ks * 32) ^ ((lane & 7) << 4)) >> 1;

    f32x16 acc[2][4] = {};                          // acc[mi][gate]

#define STAGE_A(b, h, kt) do {                                               \
        unsigned short* _d = ASB(b) + (h) * 8192 + wid * 512;                \
        const unsigned short* _s = Agb + (size_t)((h) * 128) * 4096 + (kt) * 64; \
        gl2lds16(_s, _d);                                                    \
        gl2lds16(_s + 64 * 4096, _d + 4096);                                 \
    } while (0)
#define STAGE_B(b, h, kt) do {                                               \
        unsigned short* _d = BSB(b) + (h) * 8192 + wid * 512;                \
        const unsigned short* _s = Bgb + (size_t)((h) * 128) * 4096 + (kt) * 64; \
        gl2lds16(_s, _d);                                                    \
        gl2lds16(_s + 64 * 4096, _d + 4096);                                 \
    } while (0)
#define LDA32(buf, mi, cax) (*reinterpret_cast<const bf16x8*>((buf) + (wm * 64 + (mi) * 32 + l31) * 64 + (cax)))
#define LDB32(buf, ni, cax) (*reinterpret_cast<const bf16x8*>((buf) + (wn * 128 + (ni) * 32 + l31) * 64 + (cax)))
#define SBAR() __builtin_amdgcn_s_barrier()
#define VMFENCE() asm volatile("s_waitcnt vmcnt(4)" ::: "memory")

#define KITER(T, PAR) do {                                                   \
        const unsigned short* Ac = ASB(PAR);                                 \
        const unsigned short* Bc = BSB(PAR);                                 \
        const int ktA = ((T) < 63) ? (T) + 1 : 63;                           \
        const int ktB = ((T) < 62) ? (T) + 2 : 63;                           \
        STAGE_A(PAR ^ 1, 0, ktA);                                            \
        STAGE_A(PAR ^ 1, 1, ktA);                                            \
        _Pragma("unroll")                                                    \
        for (int ks = 0; ks < 4; ++ks) {                                     \
            bf16x8 bfr[4];                                                   \
            bf16x8 af[2];                                                    \
            _Pragma("unroll")                                                \
            for (int ni = 0; ni < 4; ++ni) bfr[ni] = LDB32(Bc, ni, ca32[ks]);\
            _Pragma("unroll")                                                \
            for (int m = 0; m < 2; ++m)   af[m] = LDA32(Ac, m, ca32[ks]);    \
            __builtin_amdgcn_s_setprio(1);                                   \
            _Pragma("unroll")                                                \
            for (int m = 0; m < 2; ++m)                                      \
            _Pragma("unroll")                                                \
            for (int ni = 0; ni < 4; ++ni)                                   \
                acc[m][ni] = __builtin_amdgcn_mfma_f32_32x32x16_bf16(        \
                    af[m], bfr[ni], acc[m][ni], 0, 0, 0);                    \
            __builtin_amdgcn_s_setprio(0);                                   \
        }                                                                    \
        asm volatile("s_waitcnt lgkmcnt(0)");                                \
        __builtin_amdgcn_sched_barrier(0);                                   \
        SBAR();   /* B2: all waves' frag reads complete -> B region writable */ \
        STAGE_B(PAR, 0, ktB);                                                \
        STAGE_B(PAR, 1, ktB);                                                \
        VMFENCE();                                                           \
        SBAR();   /* B1: tile T+1 staged data ready */                       \
    } while (0)

    // ---- prologue: tile0 A+B, tile1 B staged ----
    STAGE_A(0, 0, 0); STAGE_A(0, 1, 0);
    STAGE_B(0, 0, 0); STAGE_B(0, 1, 0);
    STAGE_B(1, 0, 1); STAGE_B(1, 1, 1);
    VMFENCE();                                     // tile0's 8 loads landed
    SBAR();

    for (int u = 0; u < 32; ++u) {
        KITER(2 * u, 0);
        KITER(2 * u + 1, 1);
    }

    // ---- fused LSTM epilogue ----
    // 32x32 C/D layout: col = lane&31, row = (reg&3) + 8*(reg>>2) + 4*(lane>>5).
    // Lane l31 holds gates a,i,f,o of unit un in its 4 ni-frags (permutation above).
    const int un = bc * 64 + wn * 32 + l31;
    const float ba  = bias[un];
    const float bi  = bias[1024 + un];
    const float bfv = bias[2048 + un];
    const float bo  = bias[3072 + un];
    float* outh = out;
    float* outc = out + (size_t)4096 * 1024;

#pragma unroll
    for (int mi = 0; mi < 2; ++mi) {
        const int r0 = bm * 256 + wm * 64 + mi * 32 + 4 * q5;
#pragma unroll
        for (int reg = 0; reg < 16; ++reg) {
            const int row = r0 + (reg & 3) + 8 * (reg >> 2);
            const size_t off = (size_t)row * 1024 + un;
            const float a  = acc[mi][0][reg] + ba;
            const float ii = acc[mi][1][reg] + bi;
            const float ff = acc[mi][2][reg] + bfv;
            const float oo = acc[mi][3][reg] + bo;
            const float c  = tanh_fast(a) * sigf(ii) + sigf(ff) * cprev[off];
            outh[off] = sigf(oo) * tanh_fast(c);
            outc[off] = c;
        }
    }
#undef STAGE_A
#undef STAGE_B
#undef LDA32
#undef LDB32
#undef SBAR
#undef VMFENCE
#undef KITER
#undef ASB
#undef BSB
}

// ---------------- launch ----------------

extern "C" void kernel_launch(void* const* d_in, const int* in_sizes, int n_in,
                              void* d_out, int out_size, void* d_ws, size_t ws_size,
                              hipStream_t stream) {
    const float* top_buf = (const float*)d_in[0];
    const float* s1      = (const float*)d_in[1];
    const float* s2      = (const float*)d_in[2];
    const float* hprev   = (const float*)d_in[3];
    const float* cprev   = (const float*)d_in[4];
    const float* Wb      = (const float*)d_in[5];
    const float* W1      = (const float*)d_in[6];
    const float* W2      = (const float*)d_in[7];
    const float* Wl      = (const float*)d_in[8];
    const float* bl      = (const float*)d_in[9];

    unsigned short* Abf = (unsigned short*)d_ws;                 // 32 MB
    unsigned short* Bt  = Abf + (size_t)4096 * 4096;             // 32 MB

    convert_AB<<<32768, 256, 0, stream>>>(top_buf, s1, s2, hprev,
                                          Wb, W1, W2, Wl, Abf, Bt);

    dim3 grid(16, 16);
    gemm_lstm<<<grid, 512, 0, stream>>>(Abf, Bt, bl, cprev, (float*)d_out);
}